// Round 1
// baseline (17.243 us; speedup 1.0000x reference)
//
#include <hip/hip_runtime.h>
#include <math.h>

#define HID 768
#define RANK 5

// ---------------------------------------------------------------------------
// Kernel A: build effective factor matrices in workspace.
//   W1T[x][h],  h = i*64 + j*8 + k   (input mode index)
//   W2T[x][h],  h = p*96 + q*12 + r  (output mode index)
// block 0 -> W1T, block 1 -> W2T; 768 threads each.
// ---------------------------------------------------------------------------
__global__ void build_w(const float* __restrict__ c0, const float* __restrict__ c1,
                        const float* __restrict__ c2, const float* __restrict__ c3,
                        const float* __restrict__ c4, const float* __restrict__ c5,
                        float* __restrict__ W1T, float* __restrict__ W2T) {
    int h = threadIdx.x;
    if (h >= HID) return;
    if (blockIdx.x == 0) {
        // W1[h][x] = sum_{v,w} c0[i,v] * c1[v,j,w] * c2[w,k,x]
        int i = h >> 6, j = (h >> 3) & 7, k = h & 7;
        float acc[RANK] = {0.f, 0.f, 0.f, 0.f, 0.f};
        for (int v = 0; v < RANK; ++v) {
            float a = c0[i * RANK + v];
            for (int w = 0; w < RANK; ++w) {
                float e = a * c1[(v * 8 + j) * RANK + w];
                const float* c2p = &c2[(w * 8 + k) * RANK];
#pragma unroll
                for (int x = 0; x < RANK; ++x) acc[x] += e * c2p[x];
            }
        }
#pragma unroll
        for (int x = 0; x < RANK; ++x) W1T[x * HID + h] = acc[x];
    } else {
        // W2[x][h] = sum_{y,z} c3[x,p,y] * c4[y,q,z] * c5[z,r]
        int p = h / 96, q = (h / 12) & 7, r = h % 12;
        float acc[RANK] = {0.f, 0.f, 0.f, 0.f, 0.f};
        for (int y = 0; y < RANK; ++y) {
            for (int z = 0; z < RANK; ++z) {
                float e = c4[(y * 8 + q) * RANK + z] * c5[z * 12 + r];
#pragma unroll
                for (int x = 0; x < RANK; ++x) acc[x] += c3[(x * 8 + p) * RANK + y] * e;
            }
        }
#pragma unroll
        for (int x = 0; x < RANK; ++x) W2T[x * HID + h] = acc[x];
    }
}

// ---------------------------------------------------------------------------
// Kernel B: fused  out = hs + gelu(hs_row * W1 * W2 + bias)
// One wave (64 lanes) per row of 768. 16 waves / block (1024 threads).
// ---------------------------------------------------------------------------
__device__ __forceinline__ float gelu_f(float v) {
    return 0.5f * v * (1.0f + erff(v * 0.70710678118654752f));
}

__global__ __launch_bounds__(1024) void tt_fused(
    const float* __restrict__ x, const float* __restrict__ bias,
    const float* __restrict__ W1T, const float* __restrict__ W2T,
    float* __restrict__ out, int Btot) {
    __shared__ __align__(16) float sW1[RANK * HID];
    __shared__ __align__(16) float sW2[RANK * HID];
    __shared__ __align__(16) float sB[HID];

    const int tid = threadIdx.x;

    // Stage weights + bias into LDS (vectorized, coalesced).
    {
        const float4* g1 = reinterpret_cast<const float4*>(W1T);
        const float4* g2 = reinterpret_cast<const float4*>(W2T);
        const float4* gb = reinterpret_cast<const float4*>(bias);
        float4* s1 = reinterpret_cast<float4*>(sW1);
        float4* s2 = reinterpret_cast<float4*>(sW2);
        float4* sb = reinterpret_cast<float4*>(sB);
        if (tid < (RANK * HID) / 4) {  // 960
            s1[tid] = g1[tid];
            s2[tid] = g2[tid];
        }
        if (tid < HID / 4) sb[tid] = gb[tid];  // 192
    }

    const int lane = tid & 63;
    const int wave = tid >> 6;
    const int row = blockIdx.x * (blockDim.x >> 6) + wave;
    const bool active = row < Btot;

    // Load this wave's row: 3 coalesced float4 per lane (one HBM read total;
    // reused for the residual add).
    float4 xv0, xv1, xv2;
    if (active) {
        const float4* xr = reinterpret_cast<const float4*>(x + (size_t)row * HID);
        xv0 = xr[lane];
        xv1 = xr[lane + 64];
        xv2 = xr[lane + 128];
    }

    __syncthreads();

    if (!active) return;

    // Phase 1: t3[x] = row . W1T[x][:]  (partial per lane, then butterfly).
    float acc[RANK];
    const float4* w1v = reinterpret_cast<const float4*>(sW1);
#pragma unroll
    for (int j = 0; j < RANK; ++j) {
        float4 a = w1v[j * 192 + lane];
        float4 b = w1v[j * 192 + lane + 64];
        float4 c = w1v[j * 192 + lane + 128];
        acc[j] = xv0.x * a.x + xv0.y * a.y + xv0.z * a.z + xv0.w * a.w
               + xv1.x * b.x + xv1.y * b.y + xv1.z * b.z + xv1.w * b.w
               + xv2.x * c.x + xv2.y * c.y + xv2.z * c.z + xv2.w * c.w;
    }
#pragma unroll
    for (int off = 32; off >= 1; off >>= 1) {
#pragma unroll
        for (int j = 0; j < RANK; ++j) acc[j] += __shfl_xor(acc[j], off, 64);
    }

    // Phase 2: o[h] = bias[h] + sum_x t3[x]*W2T[x][h]; out = xv + gelu(o).
    const float4* w2v = reinterpret_cast<const float4*>(sW2);
    const float4* bv  = reinterpret_cast<const float4*>(sB);
    float4* outr = reinterpret_cast<float4*>(out + (size_t)row * HID);
#pragma unroll
    for (int t = 0; t < 3; ++t) {
        const int idx = lane + 64 * t;
        float4 o = bv[idx];
#pragma unroll
        for (int j = 0; j < RANK; ++j) {
            float4 w = w2v[j * 192 + idx];
            o.x += acc[j] * w.x;
            o.y += acc[j] * w.y;
            o.z += acc[j] * w.z;
            o.w += acc[j] * w.w;
        }
        const float4 xv = (t == 0) ? xv0 : (t == 1) ? xv1 : xv2;
        o.x = xv.x + gelu_f(o.x);
        o.y = xv.y + gelu_f(o.y);
        o.z = xv.z + gelu_f(o.z);
        o.w = xv.w + gelu_f(o.w);
        outr[idx] = o;
    }
}

extern "C" void kernel_launch(void* const* d_in, const int* in_sizes, int n_in,
                              void* d_out, int out_size, void* d_ws, size_t ws_size,
                              hipStream_t stream) {
    const float* hs   = (const float*)d_in[0];
    const float* bias = (const float*)d_in[1];
    const float* c0   = (const float*)d_in[2];
    const float* c1   = (const float*)d_in[3];
    const float* c2   = (const float*)d_in[4];
    const float* c3   = (const float*)d_in[5];
    const float* c4   = (const float*)d_in[6];
    const float* c5   = (const float*)d_in[7];
    float* W1T = (float*)d_ws;
    float* W2T = W1T + RANK * HID;
    float* out = (float*)d_out;

    const int Btot = in_sizes[0] / HID;  // 8*512 = 4096 rows

    build_w<<<2, HID, 0, stream>>>(c0, c1, c2, c3, c4, c5, W1T, W2T);

    const int wavesPerBlock = 16;  // 1024 threads
    const int grid = (Btot + wavesPerBlock - 1) / wavesPerBlock;
    tt_fused<<<grid, wavesPerBlock * 64, 0, stream>>>(hs, bias, W1T, W2T, out, Btot);
}

// Round 2
// 14.856 us; speedup vs baseline: 1.1607x; 1.1607x over previous
//
#include <hip/hip_runtime.h>
#include <math.h>

#define HID 768
#define RANK 5

// Fused: out = hs + gelu(hs_row * W1 * W2 + bias)
// W1/W2 are the collapsed TT factors (768x5 and 5x768), rebuilt redundantly
// per block (≈300 VALU ops/thread — cheaper than a separate kernel launch).
// One wave (64 lanes) per row; 16 waves/block; grid = 256 = 1 block/CU.

__device__ __forceinline__ float gelu_f(float v) {
    return 0.5f * v * (1.0f + erff(v * 0.70710678118654752f));
}

__global__ __launch_bounds__(1024) void tt_fused(
    const float* __restrict__ x, const float* __restrict__ bias,
    const float* __restrict__ c0, const float* __restrict__ c1,
    const float* __restrict__ c2, const float* __restrict__ c3,
    const float* __restrict__ c4, const float* __restrict__ c5,
    float* __restrict__ out, int Btot) {
    __shared__ __align__(16) float sW1[RANK * HID];
    __shared__ __align__(16) float sW2[RANK * HID];
    __shared__ __align__(16) float sB[HID];

    const int tid = threadIdx.x;
    const int lane = tid & 63;
    const int wave = tid >> 6;
    const int row = blockIdx.x * (blockDim.x >> 6) + wave;
    const bool active = row < Btot;

    // Issue this wave's row loads FIRST: HBM latency (~500 cyc) hides under
    // the weight-build VALU work below.
    float4 xv0, xv1, xv2;
    if (active) {
        const float4* xr = reinterpret_cast<const float4*>(x + (size_t)row * HID);
        xv0 = xr[lane];
        xv1 = xr[lane + 64];
        xv2 = xr[lane + 128];
    }

    // Build effective factors in LDS. Threads 0..767 each produce one h-column
    // of W1T (5 vals) and W2T (5 vals); threads 768.. stage bias.
    if (tid < HID) {
        const int h = tid;
        {   // W1T[x][h] = sum_{v,w} c0[i,v] * c1[v,j,w] * c2[w,k,x]
            const int i = h >> 6, j = (h >> 3) & 7, k = h & 7;
            float acc[RANK] = {0.f, 0.f, 0.f, 0.f, 0.f};
#pragma unroll
            for (int v = 0; v < RANK; ++v) {
                const float a = c0[i * RANK + v];
#pragma unroll
                for (int w = 0; w < RANK; ++w) {
                    const float e = a * c1[(v * 8 + j) * RANK + w];
                    const float* c2p = &c2[(w * 8 + k) * RANK];
#pragma unroll
                    for (int xx = 0; xx < RANK; ++xx) acc[xx] += e * c2p[xx];
                }
            }
#pragma unroll
            for (int xx = 0; xx < RANK; ++xx) sW1[xx * HID + h] = acc[xx];
        }
        {   // W2T[x][h] = sum_{y,z} c3[x,p,y] * c4[y,q,z] * c5[z,r]
            const int p = h / 96, q = (h / 12) & 7, r = h % 12;
            float acc[RANK] = {0.f, 0.f, 0.f, 0.f, 0.f};
#pragma unroll
            for (int y = 0; y < RANK; ++y) {
#pragma unroll
                for (int z = 0; z < RANK; ++z) {
                    const float e = c4[(y * 8 + q) * RANK + z] * c5[z * 12 + r];
#pragma unroll
                    for (int xx = 0; xx < RANK; ++xx)
                        acc[xx] += c3[(xx * 8 + p) * RANK + y] * e;
                }
            }
#pragma unroll
            for (int xx = 0; xx < RANK; ++xx) sW2[xx * HID + h] = acc[xx];
        }
    } else if (tid - HID < HID / 4) {
        const int t = tid - HID;  // 192 threads stage bias as float4
        reinterpret_cast<float4*>(sB)[t] = reinterpret_cast<const float4*>(bias)[t];
    }

    __syncthreads();

    if (!active) return;

    // Phase 1: t3[x] = row . W1T[x][:]  (per-lane partial, then butterfly).
    float acc[RANK];
    const float4* w1v = reinterpret_cast<const float4*>(sW1);
#pragma unroll
    for (int j = 0; j < RANK; ++j) {
        float4 a = w1v[j * 192 + lane];
        float4 b = w1v[j * 192 + lane + 64];
        float4 c = w1v[j * 192 + lane + 128];
        acc[j] = xv0.x * a.x + xv0.y * a.y + xv0.z * a.z + xv0.w * a.w
               + xv1.x * b.x + xv1.y * b.y + xv1.z * b.z + xv1.w * b.w
               + xv2.x * c.x + xv2.y * c.y + xv2.z * c.z + xv2.w * c.w;
    }
#pragma unroll
    for (int off = 32; off >= 1; off >>= 1) {
#pragma unroll
        for (int j = 0; j < RANK; ++j) acc[j] += __shfl_xor(acc[j], off, 64);
    }

    // Phase 2: o[h] = bias[h] + sum_x t3[x]*W2T[x][h]; out = xv + gelu(o).
    const float4* w2v = reinterpret_cast<const float4*>(sW2);
    const float4* bv  = reinterpret_cast<const float4*>(sB);
    float4* outr = reinterpret_cast<float4*>(out + (size_t)row * HID);
#pragma unroll
    for (int t = 0; t < 3; ++t) {
        const int idx = lane + 64 * t;
        float4 o = bv[idx];
#pragma unroll
        for (int j = 0; j < RANK; ++j) {
            float4 w = w2v[j * 192 + idx];
            o.x += acc[j] * w.x;
            o.y += acc[j] * w.y;
            o.z += acc[j] * w.z;
            o.w += acc[j] * w.w;
        }
        const float4 xv = (t == 0) ? xv0 : (t == 1) ? xv1 : xv2;
        o.x = xv.x + gelu_f(o.x);
        o.y = xv.y + gelu_f(o.y);
        o.z = xv.z + gelu_f(o.z);
        o.w = xv.w + gelu_f(o.w);
        outr[idx] = o;
    }
}

extern "C" void kernel_launch(void* const* d_in, const int* in_sizes, int n_in,
                              void* d_out, int out_size, void* d_ws, size_t ws_size,
                              hipStream_t stream) {
    const float* hs   = (const float*)d_in[0];
    const float* bias = (const float*)d_in[1];
    const float* c0   = (const float*)d_in[2];
    const float* c1   = (const float*)d_in[3];
    const float* c2   = (const float*)d_in[4];
    const float* c3   = (const float*)d_in[5];
    const float* c4   = (const float*)d_in[6];
    const float* c5   = (const float*)d_in[7];
    float* out = (float*)d_out;

    const int Btot = in_sizes[0] / HID;  // 8*512 = 4096 rows

    const int wavesPerBlock = 16;  // 1024 threads
    const int grid = (Btot + wavesPerBlock - 1) / wavesPerBlock;
    tt_fused<<<grid, wavesPerBlock * 64, 0, stream>>>(
        hs, bias, c0, c1, c2, c3, c4, c5, out, Btot);
}